// Round 8
// baseline (543.371 us; speedup 1.0000x reference)
//
#include <hip/hip_runtime.h>

#define D 256
#define BSHIFT 6
#define BSIZE 64          // nodes per bucket
#define KMAX 2048         // max buckets (LDS hist)
#define NB_P 256          // partition blocks

using bf16x8 = __attribute__((ext_vector_type(8))) short;
using f32x4  = __attribute__((ext_vector_type(4))) float;

__device__ inline float bf_lo(unsigned int u) {
    return __builtin_bit_cast(float, u << 16);
}
__device__ inline float bf_hi(unsigned int u) {
    return __builtin_bit_cast(float, u & 0xffff0000u);
}
__device__ inline unsigned short f2bf(float f) {
    unsigned int x = __builtin_bit_cast(unsigned int, f);
    unsigned int r = (x + 0x7fffu + ((x >> 16) & 1u)) >> 16;   // RNE
    return (unsigned short)r;
}

// ---------------------------------------------------------------------------
// prep: conv_feature || conv_w || histA fused via blockIdx range split.
// ---------------------------------------------------------------------------
__global__ __launch_bounds__(256) void prep_kernel(
    const float* __restrict__ feature, unsigned short* __restrict__ fbf, long n8,
    const float* __restrict__ W, unsigned short* __restrict__ Wt,
    const int* __restrict__ dst, int* __restrict__ blockHist,
    int E, int K, int chunk, int nConvF, int nConvW)
{
    __shared__ int h[KMAX];
    const int b = blockIdx.x, t = threadIdx.x;

    if (b < nConvF) {
        long i = (long)b * 256 + t;
        if (i < n8) {
            const float4* p = reinterpret_cast<const float4*>(feature + i * 8);
            float4 v0 = p[0], v1 = p[1];
            uint4 r;
            r.x = (unsigned int)f2bf(v0.x) | ((unsigned int)f2bf(v0.y) << 16);
            r.y = (unsigned int)f2bf(v0.z) | ((unsigned int)f2bf(v0.w) << 16);
            r.z = (unsigned int)f2bf(v1.x) | ((unsigned int)f2bf(v1.y) << 16);
            r.w = (unsigned int)f2bf(v1.z) | ((unsigned int)f2bf(v1.w) << 16);
            *reinterpret_cast<uint4*>(fbf + i * 8) = r;
        }
        return;
    }
    if (b < nConvF + nConvW) {
        int i = (b - nConvF) * 256 + t;
        if (i < D * D / 4) {
            int n  = i >> 6;
            int k0 = (i & 63) * 4;
            float a  = W[(size_t)(k0 + 0) * D + n];
            float bb = W[(size_t)(k0 + 1) * D + n];
            float c  = W[(size_t)(k0 + 2) * D + n];
            float d  = W[(size_t)(k0 + 3) * D + n];
            uint2 r;
            r.x = (unsigned int)f2bf(a) | ((unsigned int)f2bf(bb) << 16);
            r.y = (unsigned int)f2bf(c) | ((unsigned int)f2bf(d) << 16);
            *reinterpret_cast<uint2*>(Wt + (size_t)n * D + k0) = r;
        }
        return;
    }
    // histA
    const int hb = b - nConvF - nConvW;
    for (int i = t; i < K; i += 256) h[i] = 0;
    __syncthreads();
    const int beg = hb * chunk;
    const int end = min(beg + chunk, E);
    for (int i = beg + t; i < end; i += 256)
        atomicAdd(&h[dst[i] >> BSHIFT], 1);
    __syncthreads();
    for (int i = t; i < K; i += 256)
        blockHist[(size_t)hb * K + i] = h[i];
}

// ---------------------------------------------------------------------------
// segment sums: segsum[seg][k] = sum over 64 blocks of blockHist[b][k]
// ---------------------------------------------------------------------------
__global__ __launch_bounds__(256) void colsumA_kernel(
    const int* __restrict__ blockHist, int* __restrict__ segsum, int K)
{
    int k = blockIdx.x * 256 + threadIdx.x;
    int seg = blockIdx.y;
    if (k >= K) return;
    int s = 0;
    const int b0 = seg * 64;
    for (int b = b0; b < b0 + 64; ++b) s += blockHist[(size_t)b * K + k];
    segsum[(size_t)seg * K + k] = s;
}

// exclusive scan over bucket totals -> base[0..K], gcur = base
__global__ __launch_bounds__(1024) void basescan_kernel(
    const int* __restrict__ segsum, int* __restrict__ base,
    int* __restrict__ gcur, int K)
{
    __shared__ int sm[1024];
    const int t = threadIdx.x;
    const int chunk = (K + 1023) / 1024;
    const int b0 = min(t * chunk, K);
    const int e0 = min(b0 + chunk, K);
    int s = 0;
    for (int i = b0; i < e0; ++i)
        s += segsum[i] + segsum[K + i] + segsum[2 * K + i] + segsum[3 * K + i];
    sm[t] = s;
    __syncthreads();
    for (int off = 1; off < 1024; off <<= 1) {
        int v = (t >= off) ? sm[t - off] : 0;
        __syncthreads();
        if (t >= off) sm[t] += v;
        __syncthreads();
    }
    int run = (t == 0) ? 0 : sm[t - 1];
    for (int i = b0; i < e0; ++i) {
        base[i] = run;
        gcur[i] = run;
        run += segsum[i] + segsum[K + i] + segsum[2 * K + i] + segsum[3 * K + i];
    }
    if (e0 == K && b0 < K) base[K] = run;
}

// ---------------------------------------------------------------------------
// scatterB: read own blockHist row (no re-histogram), claim bucket ranges
// via global atomic, scatter packed (src<<6)|dstLocal grouped by bucket.
// ---------------------------------------------------------------------------
__global__ __launch_bounds__(256) void scatterB_kernel(
    const int* __restrict__ src, const int* __restrict__ dst,
    const int* __restrict__ blockHist, int* __restrict__ gcur,
    int* __restrict__ csrPacked, int E, int K, int chunk)
{
    __shared__ int cur[KMAX];
    const int b = blockIdx.x, t = threadIdx.x;
    for (int i = t; i < K; i += 256) {
        int c = blockHist[(size_t)b * K + i];
        cur[i] = c ? atomicAdd(&gcur[i], c) : 0;
    }
    __syncthreads();
    const int beg = b * chunk;
    const int end = min(beg + chunk, E);
    for (int i = beg + t; i < end; i += 256) {
        int d = dst[i];
        int k = d >> BSHIFT;
        int r = atomicAdd(&cur[k], 1);   // LDS atomic
        csrPacked[r] = (src[i] << BSHIFT) | (d & (BSIZE - 1));
    }
}

// ---------------------------------------------------------------------------
// sortC: per-bucket counting sort over 64 local nodes -> csr_src, offsets,
// counts.
// ---------------------------------------------------------------------------
__global__ __launch_bounds__(256) void sortC_kernel(
    const int* __restrict__ csrPacked, const int* __restrict__ base,
    int* __restrict__ csr_src, int* __restrict__ offsets,
    int* __restrict__ counts, int N)
{
    __shared__ int hist[BSIZE];
    __shared__ int pref[BSIZE];
    __shared__ int cur[BSIZE];
    const int k = blockIdx.x, t = threadIdx.x;
    const int beg = base[k], end = base[k + 1];

    if (t < BSIZE) hist[t] = 0;
    __syncthreads();
    for (int i = beg + t; i < end; i += 256)
        atomicAdd(&hist[csrPacked[i] & (BSIZE - 1)], 1);
    __syncthreads();
    if (t == 0) {
        int run = 0;
        for (int j = 0; j < BSIZE; ++j) { pref[j] = run; run += hist[j]; }
    }
    __syncthreads();
    if (t < BSIZE) {
        cur[t] = pref[t];
        int node = (k << BSHIFT) + t;
        if (node < N) {
            offsets[node] = beg + pref[t];
            counts[node]  = hist[t];
        }
    }
    __syncthreads();
    for (int i = beg + t; i < end; i += 256) {
        int p = csrPacked[i];
        int r = atomicAdd(&cur[p & (BSIZE - 1)], 1);   // LDS atomic
        csr_src[beg + r] = p >> BSHIFT;
    }
}

// ---------------------------------------------------------------------------
// Aggregate: one wave per node, half-wave edge split. Lanes 0-31 take even
// edges, 32-63 odd; each lane loads uint4 (8 bf16 cols), fp32 accumulate,
// __shfl_xor(.,32) merge, bf16 row write by lanes 0-31. Zero LDS -> high
// occupancy; grid 25K blocks. This kernel runs at the copy ceiling
// (1.64 GB payload @ ~6.2 TB/s L1-effective).
// ---------------------------------------------------------------------------
__global__ __launch_bounds__(256) void aggregate_kernel(
    const unsigned short* __restrict__ fbf,
    const int* __restrict__ csr_src,
    const int* __restrict__ offsets,
    const int* __restrict__ counts,
    unsigned short* __restrict__ aggb, int N)
{
    int node = blockIdx.x * 4 + (threadIdx.x >> 6);
    int lane = threadIdx.x & 63;
    if (node >= N) return;

    const int sub  = lane & 31;
    const int half = lane >> 5;
    const int beg = offsets[node];
    const int cnt = counts[node];

    float a0 = 0.f, a1 = 0.f, a2 = 0.f, a3 = 0.f;
    float a4 = 0.f, a5 = 0.f, a6 = 0.f, a7 = 0.f;

    const size_t colOff = (size_t)(sub << 3);

    int j = 0;
    for (; j + 3 < cnt; j += 4) {
        int s0 = csr_src[beg + j + half];
        int s1 = csr_src[beg + j + 2 + half];
        uint4 v0 = *reinterpret_cast<const uint4*>(fbf + ((size_t)s0 << 8) + colOff);
        uint4 v1 = *reinterpret_cast<const uint4*>(fbf + ((size_t)s1 << 8) + colOff);
        a0 += bf_lo(v0.x); a1 += bf_hi(v0.x); a2 += bf_lo(v0.y); a3 += bf_hi(v0.y);
        a4 += bf_lo(v0.z); a5 += bf_hi(v0.z); a6 += bf_lo(v0.w); a7 += bf_hi(v0.w);
        a0 += bf_lo(v1.x); a1 += bf_hi(v1.x); a2 += bf_lo(v1.y); a3 += bf_hi(v1.y);
        a4 += bf_lo(v1.z); a5 += bf_hi(v1.z); a6 += bf_lo(v1.w); a7 += bf_hi(v1.w);
    }
    if (j + 1 < cnt) {
        int s0 = csr_src[beg + j + half];
        uint4 v0 = *reinterpret_cast<const uint4*>(fbf + ((size_t)s0 << 8) + colOff);
        a0 += bf_lo(v0.x); a1 += bf_hi(v0.x); a2 += bf_lo(v0.y); a3 += bf_hi(v0.y);
        a4 += bf_lo(v0.z); a5 += bf_hi(v0.z); a6 += bf_lo(v0.w); a7 += bf_hi(v0.w);
        j += 2;
    }
    if (j < cnt && half == 0) {
        int s0 = csr_src[beg + j];
        uint4 v0 = *reinterpret_cast<const uint4*>(fbf + ((size_t)s0 << 8) + colOff);
        a0 += bf_lo(v0.x); a1 += bf_hi(v0.x); a2 += bf_lo(v0.y); a3 += bf_hi(v0.y);
        a4 += bf_lo(v0.z); a5 += bf_hi(v0.z); a6 += bf_lo(v0.w); a7 += bf_hi(v0.w);
    }

    a0 += __shfl_xor(a0, 32); a1 += __shfl_xor(a1, 32);
    a2 += __shfl_xor(a2, 32); a3 += __shfl_xor(a3, 32);
    a4 += __shfl_xor(a4, 32); a5 += __shfl_xor(a5, 32);
    a6 += __shfl_xor(a6, 32); a7 += __shfl_xor(a7, 32);

    if (half == 0) {
        uint4 r;
        r.x = (unsigned int)f2bf(a0) | ((unsigned int)f2bf(a1) << 16);
        r.y = (unsigned int)f2bf(a2) | ((unsigned int)f2bf(a3) << 16);
        r.z = (unsigned int)f2bf(a4) | ((unsigned int)f2bf(a5) << 16);
        r.w = (unsigned int)f2bf(a6) | ((unsigned int)f2bf(a7) << 16);
        *reinterpret_cast<uint4*>(aggb + ((size_t)node << 8) + colOff) = r;
    }
}

// ---------------------------------------------------------------------------
// MFMA GEMM: out[M][256] = relu(aggb[M][256] @ W + b), W as Wt[n][k] bf16.
// One wave per 16 rows; A fragments from bf16 aggb (single dwordx4 loads).
// ---------------------------------------------------------------------------
__global__ __launch_bounds__(256) void gemm_kernel(
    const unsigned short* __restrict__ A,    // [M][256] bf16
    const unsigned short* __restrict__ Wt,   // [256][256] bf16, Wt[n][k]
    const float* __restrict__ bias,
    float* __restrict__ out, int M)
{
    const int wave = threadIdx.x >> 6;
    const int lane = threadIdx.x & 63;
    const int row0 = (blockIdx.x * 4 + wave) * 16;
    if (row0 >= M) return;

    const int lr = lane & 15;
    const int lg = lane >> 4;

    bf16x8 a[8];
    const unsigned short* ap = A + (size_t)(row0 + lr) * D + lg * 8;
#pragma unroll
    for (int ks = 0; ks < 8; ++ks)
        a[ks] = *reinterpret_cast<const bf16x8*>(ap + ks * 32);

    for (int ct = 0; ct < 16; ++ct) {
        f32x4 acc = {0.f, 0.f, 0.f, 0.f};
        const unsigned short* bp = Wt + (size_t)(ct * 16 + lr) * D + lg * 8;
#pragma unroll
        for (int ks = 0; ks < 8; ++ks) {
            bf16x8 bfr = *reinterpret_cast<const bf16x8*>(bp + ks * 32);
            acc = __builtin_amdgcn_mfma_f32_16x16x32_bf16(a[ks], bfr, acc, 0, 0, 0);
        }
        const float bv = bias[ct * 16 + lr];
#pragma unroll
        for (int jj = 0; jj < 4; ++jj) {
            float v = acc[jj] + bv;
            out[(size_t)(row0 + lg * 4 + jj) * D + ct * 16 + lr] = v > 0.f ? v : 0.f;
        }
    }
}

// ---------------------------------------------------------------------------
// Fallback kernels (ws too small): direct atomic scatter + VALU linear.
// ---------------------------------------------------------------------------
__global__ __launch_bounds__(256) void scatter_kernel(
    const float* __restrict__ feature, const int* __restrict__ src,
    const int* __restrict__ dst, float* __restrict__ agg, int E)
{
    int edge = blockIdx.x * (blockDim.x >> 6) + (threadIdx.x >> 6);
    int lane = threadIdx.x & 63;
    if (edge >= E) return;
    int s = src[edge];
    int d = dst[edge];
    const float4 v = *reinterpret_cast<const float4*>(feature + (size_t)s * D + lane * 4);
    float* o = agg + (size_t)d * D + lane * 4;
    atomicAdd(o + 0, v.x);
    atomicAdd(o + 1, v.y);
    atomicAdd(o + 2, v.z);
    atomicAdd(o + 3, v.w);
}

#define BM 32
__global__ __launch_bounds__(256) void linear_relu_kernel(
    float* __restrict__ h, const float* __restrict__ W,
    const float* __restrict__ b, int n_nodes)
{
    __shared__ float sA[BM][D];
    const int node0 = blockIdx.x * BM;
    const int t = threadIdx.x;
    for (int m = 0; m < BM; ++m) {
        int nd = node0 + m;
        sA[m][t] = (nd < n_nodes) ? h[(size_t)nd * D + t] : 0.0f;
    }
    __syncthreads();
    float acc[BM];
#pragma unroll
    for (int m = 0; m < BM; ++m) acc[m] = 0.0f;
    for (int kk = 0; kk < D; ++kk) {
        float w = W[kk * D + t];
#pragma unroll
        for (int m = 0; m < BM; ++m) acc[m] += sA[m][kk] * w;
    }
    const float bias = b[t];
    for (int m = 0; m < BM; ++m) {
        int nd = node0 + m;
        if (nd < n_nodes) {
            float v = acc[m] + bias;
            h[(size_t)nd * D + t] = v > 0.0f ? v : 0.0f;
        }
    }
}

// ---------------------------------------------------------------------------
extern "C" void kernel_launch(void* const* d_in, const int* in_sizes, int n_in,
                              void* d_out, int out_size, void* d_ws, size_t ws_size,
                              hipStream_t stream)
{
    const float* feature = (const float*)d_in[0];
    const int*   src     = (const int*)d_in[1];
    const int*   dst     = (const int*)d_in[2];
    const float* W       = (const float*)d_in[3];
    const float* b       = (const float*)d_in[4];
    float*       out     = (float*)d_out;

    const int E = in_sizes[1];
    const int N = in_sizes[0] / D;
    const int K = (N + BSIZE - 1) >> BSHIFT;        // buckets
    const int chunk = (E + NB_P - 1) / NB_P;

    // ---- workspace layout -------------------------------------------------
    size_t off = 0;
    auto alloc = [&](size_t bytes, size_t align) {
        off = (off + align - 1) / align * align;
        size_t r = off; off += bytes; return r;
    };
    size_t o_bh     = alloc((size_t)NB_P * K * 4, 16);
    size_t o_seg    = alloc((size_t)4 * K * 4, 16);
    size_t o_base   = alloc((size_t)(K + 1) * 4, 16);
    size_t o_gcur   = alloc((size_t)K * 4, 16);
    size_t o_packed = alloc((size_t)E * 4, 16);
    size_t o_csr    = alloc((size_t)E * 4, 16);
    size_t o_off    = alloc((size_t)N * 4, 16);
    size_t o_cnt    = alloc((size_t)N * 4, 16);
    size_t o_wt     = alloc((size_t)D * D * 2, 16);
    size_t o_fbf    = alloc((size_t)N * D * 2, 16);
    size_t o_aggb   = alloc((size_t)N * D * 2, 16);
    size_t need_full = off;

    char* ws = (char*)d_ws;

    if (ws_size >= need_full && K <= KMAX) {
        int* blockHist = (int*)(ws + o_bh);
        int* segsum    = (int*)(ws + o_seg);
        int* base      = (int*)(ws + o_base);
        int* gcur      = (int*)(ws + o_gcur);
        int* csrPacked = (int*)(ws + o_packed);
        int* csr_src   = (int*)(ws + o_csr);
        int* offsets   = (int*)(ws + o_off);
        int* counts    = (int*)(ws + o_cnt);
        unsigned short* Wt   = (unsigned short*)(ws + o_wt);
        unsigned short* fbf  = (unsigned short*)(ws + o_fbf);
        unsigned short* aggb = (unsigned short*)(ws + o_aggb);

        const long n8 = (long)N * D / 8;
        const int nConvF = (int)((n8 + 255) / 256);
        const int nConvW = (D * D / 4 + 255) / 256;

        prep_kernel<<<nConvF + nConvW + NB_P, 256, 0, stream>>>(
            feature, fbf, n8, W, Wt, dst, blockHist, E, K, chunk, nConvF, nConvW);
        {
            dim3 g((K + 255) / 256, 4);
            colsumA_kernel<<<g, 256, 0, stream>>>(blockHist, segsum, K);
        }
        basescan_kernel<<<1, 1024, 0, stream>>>(segsum, base, gcur, K);
        scatterB_kernel<<<NB_P, 256, 0, stream>>>(
            src, dst, blockHist, gcur, csrPacked, E, K, chunk);
        sortC_kernel<<<K, 256, 0, stream>>>(
            csrPacked, base, csr_src, offsets, counts, N);

        aggregate_kernel<<<(N + 3) / 4, 256, 0, stream>>>(
            fbf, csr_src, offsets, counts, aggb, N);

        gemm_kernel<<<(N + 63) / 64, 256, 0, stream>>>(aggb, Wt, b, out, N);
    } else {
        hipMemsetAsync(d_out, 0, (size_t)out_size * sizeof(float), stream);
        scatter_kernel<<<(E + 3) / 4, 256, 0, stream>>>(feature, src, dst, out, E);
        linear_relu_kernel<<<(N + BM - 1) / BM, 256, 0, stream>>>(out, W, b, N);
    }
}

// Round 9
// 483.465 us; speedup vs baseline: 1.1239x; 1.1239x over previous
//
#include <hip/hip_runtime.h>

#define D 256
#define BSHIFT 6
#define BSIZE 64          // nodes per bucket
#define KMAX 2048         // max buckets (LDS hist)
#define NB_P 256          // partition blocks
#define TN 16             // nodes per agg_gemm block

using bf16x8 = __attribute__((ext_vector_type(8))) short;
using f32x4  = __attribute__((ext_vector_type(4))) float;

__device__ inline float bf_lo(unsigned int u) {
    return __builtin_bit_cast(float, u << 16);
}
__device__ inline float bf_hi(unsigned int u) {
    return __builtin_bit_cast(float, u & 0xffff0000u);
}
__device__ inline unsigned short f2bf(float f) {
    unsigned int x = __builtin_bit_cast(unsigned int, f);
    unsigned int r = (x + 0x7fffu + ((x >> 16) & 1u)) >> 16;   // RNE
    return (unsigned short)r;
}

// ---------------------------------------------------------------------------
// prep: conv_feature || conv_w || histA fused via blockIdx range split.
// ---------------------------------------------------------------------------
__global__ __launch_bounds__(256) void prep_kernel(
    const float* __restrict__ feature, unsigned short* __restrict__ fbf, long n8,
    const float* __restrict__ W, unsigned short* __restrict__ Wt,
    const int* __restrict__ dst, int* __restrict__ blockHist,
    int E, int K, int chunk, int nConvF, int nConvW)
{
    __shared__ int h[KMAX];
    const int b = blockIdx.x, t = threadIdx.x;

    if (b < nConvF) {
        long i = (long)b * 256 + t;
        if (i < n8) {
            const float4* p = reinterpret_cast<const float4*>(feature + i * 8);
            float4 v0 = p[0], v1 = p[1];
            uint4 r;
            r.x = (unsigned int)f2bf(v0.x) | ((unsigned int)f2bf(v0.y) << 16);
            r.y = (unsigned int)f2bf(v0.z) | ((unsigned int)f2bf(v0.w) << 16);
            r.z = (unsigned int)f2bf(v1.x) | ((unsigned int)f2bf(v1.y) << 16);
            r.w = (unsigned int)f2bf(v1.z) | ((unsigned int)f2bf(v1.w) << 16);
            *reinterpret_cast<uint4*>(fbf + i * 8) = r;
        }
        return;
    }
    if (b < nConvF + nConvW) {
        int i = (b - nConvF) * 256 + t;
        if (i < D * D / 4) {
            int n  = i >> 6;
            int k0 = (i & 63) * 4;
            float a  = W[(size_t)(k0 + 0) * D + n];
            float bb = W[(size_t)(k0 + 1) * D + n];
            float c  = W[(size_t)(k0 + 2) * D + n];
            float d  = W[(size_t)(k0 + 3) * D + n];
            uint2 r;
            r.x = (unsigned int)f2bf(a) | ((unsigned int)f2bf(bb) << 16);
            r.y = (unsigned int)f2bf(c) | ((unsigned int)f2bf(d) << 16);
            *reinterpret_cast<uint2*>(Wt + (size_t)n * D + k0) = r;
        }
        return;
    }
    // histA
    const int hb = b - nConvF - nConvW;
    for (int i = t; i < K; i += 256) h[i] = 0;
    __syncthreads();
    const int beg = hb * chunk;
    const int end = min(beg + chunk, E);
    for (int i = beg + t; i < end; i += 256)
        atomicAdd(&h[dst[i] >> BSHIFT], 1);
    __syncthreads();
    for (int i = t; i < K; i += 256)
        blockHist[(size_t)hb * K + i] = h[i];
}

// ---------------------------------------------------------------------------
// claimB: per-bucket column sum over blockHist + atomic claim of a contiguous
// region (bucket region order is arbitrary; only contiguity matters).
// Replaces colsumA + basescan.
// ---------------------------------------------------------------------------
__global__ __launch_bounds__(256) void claimB_kernel(
    const int* __restrict__ blockHist, int* __restrict__ bbeg,
    int* __restrict__ bcnt, int* __restrict__ gcur, int* __restrict__ ctr,
    int K)
{
    int k = blockIdx.x * 256 + threadIdx.x;
    if (k >= K) return;
    int s = 0;
    for (int b = 0; b < NB_P; ++b) s += blockHist[(size_t)b * K + k];
    int base = s ? atomicAdd(ctr, s) : 0;
    bbeg[k] = base;
    bcnt[k] = s;
    gcur[k] = base;
}

// ---------------------------------------------------------------------------
// scatterB: read own blockHist row, claim per-block sub-ranges via global
// atomic on gcur, scatter packed (src<<6)|dstLocal grouped by bucket.
// ---------------------------------------------------------------------------
__global__ __launch_bounds__(256) void scatterB_kernel(
    const int* __restrict__ src, const int* __restrict__ dst,
    const int* __restrict__ blockHist, int* __restrict__ gcur,
    int* __restrict__ csrPacked, int E, int K, int chunk)
{
    __shared__ int cur[KMAX];
    const int b = blockIdx.x, t = threadIdx.x;
    for (int i = t; i < K; i += 256) {
        int c = blockHist[(size_t)b * K + i];
        cur[i] = c ? atomicAdd(&gcur[i], c) : 0;
    }
    __syncthreads();
    const int beg = b * chunk;
    const int end = min(beg + chunk, E);
    for (int i = beg + t; i < end; i += 256) {
        int d = dst[i];
        int k = d >> BSHIFT;
        int r = atomicAdd(&cur[k], 1);   // LDS atomic
        csrPacked[r] = (src[i] << BSHIFT) | (d & (BSIZE - 1));
    }
}

// ---------------------------------------------------------------------------
// sortC: per-bucket counting sort over 64 local nodes -> csr_src, offsets,
// counts. Bucket region = [bbeg[k], bbeg[k]+bcnt[k]).
// ---------------------------------------------------------------------------
__global__ __launch_bounds__(256) void sortC_kernel(
    const int* __restrict__ csrPacked, const int* __restrict__ bbeg,
    const int* __restrict__ bcnt,
    int* __restrict__ csr_src, int* __restrict__ offsets,
    int* __restrict__ counts, int N)
{
    __shared__ int hist[BSIZE];
    __shared__ int pref[BSIZE];
    __shared__ int cur[BSIZE];
    const int k = blockIdx.x, t = threadIdx.x;
    const int beg = bbeg[k], end = beg + bcnt[k];

    if (t < BSIZE) hist[t] = 0;
    __syncthreads();
    for (int i = beg + t; i < end; i += 256)
        atomicAdd(&hist[csrPacked[i] & (BSIZE - 1)], 1);
    __syncthreads();
    if (t == 0) {
        int run = 0;
        for (int j = 0; j < BSIZE; ++j) { pref[j] = run; run += hist[j]; }
    }
    __syncthreads();
    if (t < BSIZE) {
        cur[t] = pref[t];
        int node = (k << BSHIFT) + t;
        if (node < N) {
            offsets[node] = beg + pref[t];
            counts[node]  = hist[t];
        }
    }
    __syncthreads();
    for (int i = beg + t; i < end; i += 256) {
        int p = csrPacked[i];
        int r = atomicAdd(&cur[p & (BSIZE - 1)], 1);   // LDS atomic
        csr_src[beg + r] = p >> BSHIFT;
    }
}

// ---------------------------------------------------------------------------
// Fused aggregate + GEMM at 16-node granularity.
// Phase 1 (gather): 4 waves x 4 nodes each; per node, half-wave edge split
// (lanes 0-31 even edges, 32-63 odd), uint4 loads (8 bf16 cols/lane), fp32
// accumulate, shfl_xor merge, bf16 row -> LDS tile A[16][264].
// Phase 2 (GEMM): 16x256 @ 256x256 MFMA; wave w owns column tiles
// [4w,4w+4); + bias + ReLU -> out (fp32). No aggb round-trip.
// LDS 8.4 KB -> occupancy unchanged vs the standalone gather kernel.
// ---------------------------------------------------------------------------
__global__ __launch_bounds__(256) void agg_gemm_kernel(
    const unsigned short* __restrict__ fbf,
    const int* __restrict__ csr_src,
    const int* __restrict__ offsets,
    const int* __restrict__ counts,
    const unsigned short* __restrict__ Wt,
    const float* __restrict__ bias,
    float* __restrict__ out, int N)
{
    __shared__ unsigned short A[TN][D + 8];    // 8448 B, +8 pad

    const int wave = threadIdx.x >> 6;
    const int lane = threadIdx.x & 63;
    const int sub  = lane & 31;
    const int half = lane >> 5;
    const int node0 = blockIdx.x * TN;
    const size_t colOff = (size_t)(sub << 3);

    // ---- Phase 1: gather 4 nodes per wave ----
    for (int ni = 0; ni < 4; ++ni) {
        const int l = (wave << 2) + ni;
        const int node = node0 + l;
        float a0 = 0.f, a1 = 0.f, a2 = 0.f, a3 = 0.f;
        float a4 = 0.f, a5 = 0.f, a6 = 0.f, a7 = 0.f;
        if (node < N) {
            const int beg = offsets[node];
            const int cnt = counts[node];
            int j = 0;
            for (; j + 3 < cnt; j += 4) {
                int s0 = csr_src[beg + j + half];
                int s1 = csr_src[beg + j + 2 + half];
                uint4 v0 = *reinterpret_cast<const uint4*>(fbf + ((size_t)s0 << 8) + colOff);
                uint4 v1 = *reinterpret_cast<const uint4*>(fbf + ((size_t)s1 << 8) + colOff);
                a0 += bf_lo(v0.x); a1 += bf_hi(v0.x); a2 += bf_lo(v0.y); a3 += bf_hi(v0.y);
                a4 += bf_lo(v0.z); a5 += bf_hi(v0.z); a6 += bf_lo(v0.w); a7 += bf_hi(v0.w);
                a0 += bf_lo(v1.x); a1 += bf_hi(v1.x); a2 += bf_lo(v1.y); a3 += bf_hi(v1.y);
                a4 += bf_lo(v1.z); a5 += bf_hi(v1.z); a6 += bf_lo(v1.w); a7 += bf_hi(v1.w);
            }
            if (j + 1 < cnt) {
                int s0 = csr_src[beg + j + half];
                uint4 v0 = *reinterpret_cast<const uint4*>(fbf + ((size_t)s0 << 8) + colOff);
                a0 += bf_lo(v0.x); a1 += bf_hi(v0.x); a2 += bf_lo(v0.y); a3 += bf_hi(v0.y);
                a4 += bf_lo(v0.z); a5 += bf_hi(v0.z); a6 += bf_lo(v0.w); a7 += bf_hi(v0.w);
                j += 2;
            }
            if (j < cnt && half == 0) {
                int s0 = csr_src[beg + j];
                uint4 v0 = *reinterpret_cast<const uint4*>(fbf + ((size_t)s0 << 8) + colOff);
                a0 += bf_lo(v0.x); a1 += bf_hi(v0.x); a2 += bf_lo(v0.y); a3 += bf_hi(v0.y);
                a4 += bf_lo(v0.z); a5 += bf_hi(v0.z); a6 += bf_lo(v0.w); a7 += bf_hi(v0.w);
            }
        }
        a0 += __shfl_xor(a0, 32); a1 += __shfl_xor(a1, 32);
        a2 += __shfl_xor(a2, 32); a3 += __shfl_xor(a3, 32);
        a4 += __shfl_xor(a4, 32); a5 += __shfl_xor(a5, 32);
        a6 += __shfl_xor(a6, 32); a7 += __shfl_xor(a7, 32);
        if (half == 0) {
            uint4 r;
            r.x = (unsigned int)f2bf(a0) | ((unsigned int)f2bf(a1) << 16);
            r.y = (unsigned int)f2bf(a2) | ((unsigned int)f2bf(a3) << 16);
            r.z = (unsigned int)f2bf(a4) | ((unsigned int)f2bf(a5) << 16);
            r.w = (unsigned int)f2bf(a6) | ((unsigned int)f2bf(a7) << 16);
            *reinterpret_cast<uint4*>(&A[l][sub << 3]) = r;
        }
    }
    __syncthreads();

    // ---- Phase 2: GEMM 16x256 ----
    const int lr = lane & 15;
    const int lg = lane >> 4;

    bf16x8 afr[8];
#pragma unroll
    for (int ks = 0; ks < 8; ++ks)
        afr[ks] = *reinterpret_cast<const bf16x8*>(&A[lr][ks * 32 + lg * 8]);

#pragma unroll
    for (int c = 0; c < 4; ++c) {
        const int ct = (wave << 2) + c;
        f32x4 acc = {0.f, 0.f, 0.f, 0.f};
        const unsigned short* bp = Wt + (size_t)(ct * 16 + lr) * D + lg * 8;
#pragma unroll
        for (int ks = 0; ks < 8; ++ks) {
            bf16x8 bfr = *reinterpret_cast<const bf16x8*>(bp + ks * 32);
            acc = __builtin_amdgcn_mfma_f32_16x16x32_bf16(afr[ks], bfr, acc, 0, 0, 0);
        }
        const float bv = bias[ct * 16 + lr];
#pragma unroll
        for (int jj = 0; jj < 4; ++jj) {
            int row = node0 + lg * 4 + jj;
            if (row < N) {
                float v = acc[jj] + bv;
                out[(size_t)row * D + ct * 16 + lr] = v > 0.f ? v : 0.f;
            }
        }
    }
}

// ---------------------------------------------------------------------------
// Fallback kernels (ws too small): direct atomic scatter + VALU linear.
// ---------------------------------------------------------------------------
__global__ __launch_bounds__(256) void scatter_kernel(
    const float* __restrict__ feature, const int* __restrict__ src,
    const int* __restrict__ dst, float* __restrict__ agg, int E)
{
    int edge = blockIdx.x * (blockDim.x >> 6) + (threadIdx.x >> 6);
    int lane = threadIdx.x & 63;
    if (edge >= E) return;
    int s = src[edge];
    int d = dst[edge];
    const float4 v = *reinterpret_cast<const float4*>(feature + (size_t)s * D + lane * 4);
    float* o = agg + (size_t)d * D + lane * 4;
    atomicAdd(o + 0, v.x);
    atomicAdd(o + 1, v.y);
    atomicAdd(o + 2, v.z);
    atomicAdd(o + 3, v.w);
}

#define BM 32
__global__ __launch_bounds__(256) void linear_relu_kernel(
    float* __restrict__ h, const float* __restrict__ W,
    const float* __restrict__ b, int n_nodes)
{
    __shared__ float sA[BM][D];
    const int node0 = blockIdx.x * BM;
    const int t = threadIdx.x;
    for (int m = 0; m < BM; ++m) {
        int nd = node0 + m;
        sA[m][t] = (nd < n_nodes) ? h[(size_t)nd * D + t] : 0.0f;
    }
    __syncthreads();
    float acc[BM];
#pragma unroll
    for (int m = 0; m < BM; ++m) acc[m] = 0.0f;
    for (int kk = 0; kk < D; ++kk) {
        float w = W[kk * D + t];
#pragma unroll
        for (int m = 0; m < BM; ++m) acc[m] += sA[m][kk] * w;
    }
    const float bias = b[t];
    for (int m = 0; m < BM; ++m) {
        int nd = node0 + m;
        if (nd < n_nodes) {
            float v = acc[m] + bias;
            h[(size_t)nd * D + t] = v > 0.0f ? v : 0.0f;
        }
    }
}

// ---------------------------------------------------------------------------
extern "C" void kernel_launch(void* const* d_in, const int* in_sizes, int n_in,
                              void* d_out, int out_size, void* d_ws, size_t ws_size,
                              hipStream_t stream)
{
    const float* feature = (const float*)d_in[0];
    const int*   src     = (const int*)d_in[1];
    const int*   dst     = (const int*)d_in[2];
    const float* W       = (const float*)d_in[3];
    const float* b       = (const float*)d_in[4];
    float*       out     = (float*)d_out;

    const int E = in_sizes[1];
    const int N = in_sizes[0] / D;
    const int K = (N + BSIZE - 1) >> BSHIFT;        // buckets
    const int chunk = (E + NB_P - 1) / NB_P;

    // ---- workspace layout -------------------------------------------------
    size_t off = 0;
    auto alloc = [&](size_t bytes, size_t align) {
        off = (off + align - 1) / align * align;
        size_t r = off; off += bytes; return r;
    };
    size_t o_bh     = alloc((size_t)NB_P * K * 4, 16);
    size_t o_bbeg   = alloc((size_t)K * 4, 16);
    size_t o_bcnt   = alloc((size_t)K * 4, 16);
    size_t o_gcur   = alloc((size_t)K * 4, 16);
    size_t o_ctr    = alloc(16, 16);
    size_t o_packed = alloc((size_t)E * 4, 16);
    size_t o_csr    = alloc((size_t)E * 4, 16);
    size_t o_off    = alloc((size_t)N * 4, 16);
    size_t o_cnt    = alloc((size_t)N * 4, 16);
    size_t o_wt     = alloc((size_t)D * D * 2, 16);
    size_t o_fbf    = alloc((size_t)N * D * 2, 16);
    size_t need_full = off;

    char* ws = (char*)d_ws;

    if (ws_size >= need_full && K <= KMAX) {
        int* blockHist = (int*)(ws + o_bh);
        int* bbeg      = (int*)(ws + o_bbeg);
        int* bcnt      = (int*)(ws + o_bcnt);
        int* gcur      = (int*)(ws + o_gcur);
        int* ctr       = (int*)(ws + o_ctr);
        int* csrPacked = (int*)(ws + o_packed);
        int* csr_src   = (int*)(ws + o_csr);
        int* offsets   = (int*)(ws + o_off);
        int* counts    = (int*)(ws + o_cnt);
        unsigned short* Wt  = (unsigned short*)(ws + o_wt);
        unsigned short* fbf = (unsigned short*)(ws + o_fbf);

        const long n8 = (long)N * D / 8;
        const int nConvF = (int)((n8 + 255) / 256);
        const int nConvW = (D * D / 4 + 255) / 256;

        hipMemsetAsync(ctr, 0, 4, stream);

        prep_kernel<<<nConvF + nConvW + NB_P, 256, 0, stream>>>(
            feature, fbf, n8, W, Wt, dst, blockHist, E, K, chunk, nConvF, nConvW);

        claimB_kernel<<<(K + 255) / 256, 256, 0, stream>>>(
            blockHist, bbeg, bcnt, gcur, ctr, K);

        scatterB_kernel<<<NB_P, 256, 0, stream>>>(
            src, dst, blockHist, gcur, csrPacked, E, K, chunk);

        sortC_kernel<<<K, 256, 0, stream>>>(
            csrPacked, bbeg, bcnt, csr_src, offsets, counts, N);

        agg_gemm_kernel<<<(N + TN - 1) / TN, 256, 0, stream>>>(
            fbf, csr_src, offsets, counts, Wt, b, out, N);
    } else {
        hipMemsetAsync(d_out, 0, (size_t)out_size * sizeof(float), stream);
        scatter_kernel<<<(E + 3) / 4, 256, 0, stream>>>(feature, src, dst, out, E);
        linear_relu_kernel<<<(N + BM - 1) / BM, 256, 0, stream>>>(out, W, b, N);
    }
}

// Round 10
// 451.714 us; speedup vs baseline: 1.2029x; 1.0703x over previous
//
#include <hip/hip_runtime.h>

#define D 256
#define GSHIFT 4
#define GSIZE 16          // nodes per group (= nodes per agg_gemm block)
#define KMAX4 6400        // max groups (LDS hist: 25.6 KB)
#define NB_P 256          // partition blocks
#define TN 16             // nodes per agg_gemm block
#define CAP 1024          // max edges per group in LDS (mean 512, ~22 sigma)

using bf16x8 = __attribute__((ext_vector_type(8))) short;
using f32x4  = __attribute__((ext_vector_type(4))) float;

__device__ inline float bf_lo(unsigned int u) {
    return __builtin_bit_cast(float, u << 16);
}
__device__ inline float bf_hi(unsigned int u) {
    return __builtin_bit_cast(float, u & 0xffff0000u);
}
__device__ inline unsigned short f2bf(float f) {
    unsigned int x = __builtin_bit_cast(unsigned int, f);
    unsigned int r = (x + 0x7fffu + ((x >> 16) & 1u)) >> 16;   // RNE
    return (unsigned short)r;
}

// ---------------------------------------------------------------------------
// prep: conv_feature || conv_w || hist(dst>>4) fused via blockIdx range split.
// ---------------------------------------------------------------------------
__global__ __launch_bounds__(256) void prep_kernel(
    const float* __restrict__ feature, unsigned short* __restrict__ fbf, long n8,
    const float* __restrict__ W, unsigned short* __restrict__ Wt,
    const int* __restrict__ dst, int* __restrict__ blockHist,
    int E, int K, int chunk, int nConvF, int nConvW)
{
    __shared__ int h[KMAX4];
    const int b = blockIdx.x, t = threadIdx.x;

    if (b < nConvF) {
        long i = (long)b * 256 + t;
        if (i < n8) {
            const float4* p = reinterpret_cast<const float4*>(feature + i * 8);
            float4 v0 = p[0], v1 = p[1];
            uint4 r;
            r.x = (unsigned int)f2bf(v0.x) | ((unsigned int)f2bf(v0.y) << 16);
            r.y = (unsigned int)f2bf(v0.z) | ((unsigned int)f2bf(v0.w) << 16);
            r.z = (unsigned int)f2bf(v1.x) | ((unsigned int)f2bf(v1.y) << 16);
            r.w = (unsigned int)f2bf(v1.z) | ((unsigned int)f2bf(v1.w) << 16);
            *reinterpret_cast<uint4*>(fbf + i * 8) = r;
        }
        return;
    }
    if (b < nConvF + nConvW) {
        int i = (b - nConvF) * 256 + t;
        if (i < D * D / 4) {
            int n  = i >> 6;
            int k0 = (i & 63) * 4;
            float a  = W[(size_t)(k0 + 0) * D + n];
            float bb = W[(size_t)(k0 + 1) * D + n];
            float c  = W[(size_t)(k0 + 2) * D + n];
            float d  = W[(size_t)(k0 + 3) * D + n];
            uint2 r;
            r.x = (unsigned int)f2bf(a) | ((unsigned int)f2bf(bb) << 16);
            r.y = (unsigned int)f2bf(c) | ((unsigned int)f2bf(d) << 16);
            *reinterpret_cast<uint2*>(Wt + (size_t)n * D + k0) = r;
        }
        return;
    }
    // hist at 16-node-group granularity
    const int hb = b - nConvF - nConvW;
    for (int i = t; i < K; i += 256) h[i] = 0;
    __syncthreads();
    const int beg = hb * chunk;
    const int end = min(beg + chunk, E);
    for (int i = beg + t; i < end; i += 256)
        atomicAdd(&h[dst[i] >> GSHIFT], 1);
    __syncthreads();
    for (int i = t; i < K; i += 256)
        blockHist[(size_t)hb * K + i] = h[i];
}

// ---------------------------------------------------------------------------
// claimB: per-group column sum over blockHist + atomic claim of a contiguous
// region (region order arbitrary; only contiguity matters).
// ---------------------------------------------------------------------------
__global__ __launch_bounds__(256) void claimB_kernel(
    const int* __restrict__ blockHist, int* __restrict__ bbeg,
    int* __restrict__ bcnt, int* __restrict__ gcur, int* __restrict__ ctr,
    int K)
{
    int k = blockIdx.x * 256 + threadIdx.x;
    if (k >= K) return;
    int s = 0;
    for (int b = 0; b < NB_P; ++b) s += blockHist[(size_t)b * K + k];
    int base = s ? atomicAdd(ctr, s) : 0;
    bbeg[k] = base;
    bcnt[k] = s;
    gcur[k] = base;
}

// ---------------------------------------------------------------------------
// scatterB: read own blockHist row, claim per-block sub-ranges via global
// atomic on gcur, scatter packed (src<<4)|dstLocal grouped by 16-node group.
// ---------------------------------------------------------------------------
__global__ __launch_bounds__(256) void scatterB_kernel(
    const int* __restrict__ src, const int* __restrict__ dst,
    const int* __restrict__ blockHist, int* __restrict__ gcur,
    int* __restrict__ csrPacked, int E, int K, int chunk)
{
    __shared__ int cur[KMAX4];
    const int b = blockIdx.x, t = threadIdx.x;
    for (int i = t; i < K; i += 256) {
        int c = blockHist[(size_t)b * K + i];
        cur[i] = c ? atomicAdd(&gcur[i], c) : 0;
    }
    __syncthreads();
    const int beg = b * chunk;
    const int end = min(beg + chunk, E);
    for (int i = beg + t; i < end; i += 256) {
        int d = dst[i];
        int k = d >> GSHIFT;
        int r = atomicAdd(&cur[k], 1);   // LDS atomic
        csrPacked[r] = (src[i] << GSHIFT) | (d & (GSIZE - 1));
    }
}

// ---------------------------------------------------------------------------
// Fused in-LDS sort + aggregate + GEMM at 16-node granularity.
// Block b owns group b = nodes [16b, 16b+16), edges [bbeg[b], bbeg[b]+bcnt[b]).
// P0: counting sort of the group's packed edges into lsrc (LDS, 2 L2 passes).
// P1: gather: 4 waves x 4 nodes; half-wave edge split (lanes 0-31 even edges,
//     32-63 odd), uint4 loads (8 bf16 cols/lane), fp32 acc, shfl_xor merge,
//     bf16 row -> LDS A[16][264].
// P2: GEMM 16x256 @ 256x256 MFMA; wave w owns col-tiles [4w,4w+4);
//     + bias + ReLU -> out (fp32).
// LDS ~12.7 KB -> 8 blocks/CU (wave-limited), gather concurrency preserved.
// ---------------------------------------------------------------------------
__global__ __launch_bounds__(256) void agg_gemm_kernel(
    const unsigned short* __restrict__ fbf,
    const int* __restrict__ csrPacked,
    const int* __restrict__ bbeg,
    const int* __restrict__ bcnt,
    const unsigned short* __restrict__ Wt,
    const float* __restrict__ bias,
    float* __restrict__ out, int N)
{
    __shared__ int lsrc[CAP];
    __shared__ int nBeg[TN], nCnt[TN], nCur[TN];
    __shared__ unsigned short A[TN][D + 8];    // 8448 B, +8 pad

    const int blk  = blockIdx.x;
    const int t    = threadIdx.x;
    const int wave = t >> 6;
    const int lane = t & 63;
    const int sub  = lane & 31;
    const int half = lane >> 5;
    const int node0 = blk * TN;
    const size_t colOff = (size_t)(sub << 3);

    const int beg = bbeg[blk];
    const int cnt = bcnt[blk];

    if (cnt <= CAP) {
        // ---- P0: counting sort into lsrc grouped by local node ----
        if (t < TN) nCnt[t] = 0;
        __syncthreads();
        for (int i = t; i < cnt; i += 256)
            atomicAdd(&nCnt[csrPacked[beg + i] & (GSIZE - 1)], 1);
        __syncthreads();
        if (t == 0) {
            int run = 0;
            for (int j = 0; j < TN; ++j) { nBeg[j] = run; run += nCnt[j]; }
        }
        __syncthreads();
        if (t < TN) nCur[t] = nBeg[t];
        __syncthreads();
        for (int i = t; i < cnt; i += 256) {
            int p = csrPacked[beg + i];
            int r = atomicAdd(&nCur[p & (GSIZE - 1)], 1);
            lsrc[r] = p >> GSHIFT;
        }
        __syncthreads();

        // ---- P1: gather 4 nodes per wave ----
        for (int ni = 0; ni < 4; ++ni) {
            const int l = (wave << 2) + ni;
            const int node = node0 + l;
            float a0 = 0.f, a1 = 0.f, a2 = 0.f, a3 = 0.f;
            float a4 = 0.f, a5 = 0.f, a6 = 0.f, a7 = 0.f;
            if (node < N) {
                const int b0 = nBeg[l];
                const int c0 = nCnt[l];
                int j = 0;
                for (; j + 3 < c0; j += 4) {
                    int s0 = lsrc[b0 + j + half];
                    int s1 = lsrc[b0 + j + 2 + half];
                    uint4 v0 = *reinterpret_cast<const uint4*>(fbf + ((size_t)s0 << 8) + colOff);
                    uint4 v1 = *reinterpret_cast<const uint4*>(fbf + ((size_t)s1 << 8) + colOff);
                    a0 += bf_lo(v0.x); a1 += bf_hi(v0.x); a2 += bf_lo(v0.y); a3 += bf_hi(v0.y);
                    a4 += bf_lo(v0.z); a5 += bf_hi(v0.z); a6 += bf_lo(v0.w); a7 += bf_hi(v0.w);
                    a0 += bf_lo(v1.x); a1 += bf_hi(v1.x); a2 += bf_lo(v1.y); a3 += bf_hi(v1.y);
                    a4 += bf_lo(v1.z); a5 += bf_hi(v1.z); a6 += bf_lo(v1.w); a7 += bf_hi(v1.w);
                }
                if (j + 1 < c0) {
                    int s0 = lsrc[b0 + j + half];
                    uint4 v0 = *reinterpret_cast<const uint4*>(fbf + ((size_t)s0 << 8) + colOff);
                    a0 += bf_lo(v0.x); a1 += bf_hi(v0.x); a2 += bf_lo(v0.y); a3 += bf_hi(v0.y);
                    a4 += bf_lo(v0.z); a5 += bf_hi(v0.z); a6 += bf_lo(v0.w); a7 += bf_hi(v0.w);
                    j += 2;
                }
                if (j < c0 && half == 0) {
                    int s0 = lsrc[b0 + j];
                    uint4 v0 = *reinterpret_cast<const uint4*>(fbf + ((size_t)s0 << 8) + colOff);
                    a0 += bf_lo(v0.x); a1 += bf_hi(v0.x); a2 += bf_lo(v0.y); a3 += bf_hi(v0.y);
                    a4 += bf_lo(v0.z); a5 += bf_hi(v0.z); a6 += bf_lo(v0.w); a7 += bf_hi(v0.w);
                }
            }
            a0 += __shfl_xor(a0, 32); a1 += __shfl_xor(a1, 32);
            a2 += __shfl_xor(a2, 32); a3 += __shfl_xor(a3, 32);
            a4 += __shfl_xor(a4, 32); a5 += __shfl_xor(a5, 32);
            a6 += __shfl_xor(a6, 32); a7 += __shfl_xor(a7, 32);
            if (half == 0) {
                uint4 r;
                r.x = (unsigned int)f2bf(a0) | ((unsigned int)f2bf(a1) << 16);
                r.y = (unsigned int)f2bf(a2) | ((unsigned int)f2bf(a3) << 16);
                r.z = (unsigned int)f2bf(a4) | ((unsigned int)f2bf(a5) << 16);
                r.w = (unsigned int)f2bf(a6) | ((unsigned int)f2bf(a7) << 16);
                *reinterpret_cast<uint4*>(&A[l][sub << 3]) = r;
            }
        }
    } else {
        // ---- slow path (statistically never): per-node scan of the range ----
        for (int ni = 0; ni < 4; ++ni) {
            const int l = (wave << 2) + ni;
            const int node = node0 + l;
            float c0 = 0.f, c1 = 0.f, c2 = 0.f, c3 = 0.f;
            if (node < N) {
                for (int j = 0; j < cnt; ++j) {
                    int p = csrPacked[beg + j];
                    if ((p & (GSIZE - 1)) == l) {
                        uint2 v = *reinterpret_cast<const uint2*>(
                            fbf + ((size_t)(p >> GSHIFT) << 8) + (lane << 2));
                        c0 += bf_lo(v.x); c1 += bf_hi(v.x);
                        c2 += bf_lo(v.y); c3 += bf_hi(v.y);
                    }
                }
            }
            uint2 r;
            r.x = (unsigned int)f2bf(c0) | ((unsigned int)f2bf(c1) << 16);
            r.y = (unsigned int)f2bf(c2) | ((unsigned int)f2bf(c3) << 16);
            *reinterpret_cast<uint2*>(&A[l][lane << 2]) = r;
        }
    }
    __syncthreads();

    // ---- P2: GEMM 16x256 ----
    const int lr = lane & 15;
    const int lg = lane >> 4;

    bf16x8 afr[8];
#pragma unroll
    for (int ks = 0; ks < 8; ++ks)
        afr[ks] = *reinterpret_cast<const bf16x8*>(&A[lr][ks * 32 + lg * 8]);

#pragma unroll
    for (int c = 0; c < 4; ++c) {
        const int ct = (wave << 2) + c;
        f32x4 acc = {0.f, 0.f, 0.f, 0.f};
        const unsigned short* bp = Wt + (size_t)(ct * 16 + lr) * D + lg * 8;
#pragma unroll
        for (int ks = 0; ks < 8; ++ks) {
            bf16x8 bfr = *reinterpret_cast<const bf16x8*>(bp + ks * 32);
            acc = __builtin_amdgcn_mfma_f32_16x16x32_bf16(afr[ks], bfr, acc, 0, 0, 0);
        }
        const float bv = bias[ct * 16 + lr];
#pragma unroll
        for (int jj = 0; jj < 4; ++jj) {
            int row = node0 + lg * 4 + jj;
            if (row < N) {
                float v = acc[jj] + bv;
                out[(size_t)row * D + ct * 16 + lr] = v > 0.f ? v : 0.f;
            }
        }
    }
}

// ---------------------------------------------------------------------------
// Fallback kernels (ws too small): direct atomic scatter + VALU linear.
// ---------------------------------------------------------------------------
__global__ __launch_bounds__(256) void scatter_kernel(
    const float* __restrict__ feature, const int* __restrict__ src,
    const int* __restrict__ dst, float* __restrict__ agg, int E)
{
    int edge = blockIdx.x * (blockDim.x >> 6) + (threadIdx.x >> 6);
    int lane = threadIdx.x & 63;
    if (edge >= E) return;
    int s = src[edge];
    int d = dst[edge];
    const float4 v = *reinterpret_cast<const float4*>(feature + (size_t)s * D + lane * 4);
    float* o = agg + (size_t)d * D + lane * 4;
    atomicAdd(o + 0, v.x);
    atomicAdd(o + 1, v.y);
    atomicAdd(o + 2, v.z);
    atomicAdd(o + 3, v.w);
}

#define BM 32
__global__ __launch_bounds__(256) void linear_relu_kernel(
    float* __restrict__ h, const float* __restrict__ W,
    const float* __restrict__ b, int n_nodes)
{
    __shared__ float sA[BM][D];
    const int node0 = blockIdx.x * BM;
    const int t = threadIdx.x;
    for (int m = 0; m < BM; ++m) {
        int nd = node0 + m;
        sA[m][t] = (nd < n_nodes) ? h[(size_t)nd * D + t] : 0.0f;
    }
    __syncthreads();
    float acc[BM];
#pragma unroll
    for (int m = 0; m < BM; ++m) acc[m] = 0.0f;
    for (int kk = 0; kk < D; ++kk) {
        float w = W[kk * D + t];
#pragma unroll
        for (int m = 0; m < BM; ++m) acc[m] += sA[m][kk] * w;
    }
    const float bias = b[t];
    for (int m = 0; m < BM; ++m) {
        int nd = node0 + m;
        if (nd < n_nodes) {
            float v = acc[m] + bias;
            h[(size_t)nd * D + t] = v > 0.0f ? v : 0.0f;
        }
    }
}

// ---------------------------------------------------------------------------
extern "C" void kernel_launch(void* const* d_in, const int* in_sizes, int n_in,
                              void* d_out, int out_size, void* d_ws, size_t ws_size,
                              hipStream_t stream)
{
    const float* feature = (const float*)d_in[0];
    const int*   src     = (const int*)d_in[1];
    const int*   dst     = (const int*)d_in[2];
    const float* W       = (const float*)d_in[3];
    const float* b       = (const float*)d_in[4];
    float*       out     = (float*)d_out;

    const int E = in_sizes[1];
    const int N = in_sizes[0] / D;
    const int K = (N + GSIZE - 1) >> GSHIFT;        // 16-node groups
    const int chunk = (E + NB_P - 1) / NB_P;

    // ---- workspace layout -------------------------------------------------
    size_t off = 0;
    auto alloc = [&](size_t bytes, size_t align) {
        off = (off + align - 1) / align * align;
        size_t r = off; off += bytes; return r;
    };
    size_t o_bh     = alloc((size_t)NB_P * K * 4, 16);
    size_t o_bbeg   = alloc((size_t)K * 4, 16);
    size_t o_bcnt   = alloc((size_t)K * 4, 16);
    size_t o_gcur   = alloc((size_t)K * 4, 16);
    size_t o_ctr    = alloc(16, 16);
    size_t o_packed = alloc((size_t)E * 4, 16);
    size_t o_wt     = alloc((size_t)D * D * 2, 16);
    size_t o_fbf    = alloc((size_t)N * D * 2, 16);
    size_t need_full = off;

    char* ws = (char*)d_ws;

    if (ws_size >= need_full && K <= KMAX4) {
        int* blockHist = (int*)(ws + o_bh);
        int* bbeg      = (int*)(ws + o_bbeg);
        int* bcnt      = (int*)(ws + o_bcnt);
        int* gcur      = (int*)(ws + o_gcur);
        int* ctr       = (int*)(ws + o_ctr);
        int* csrPacked = (int*)(ws + o_packed);
        unsigned short* Wt  = (unsigned short*)(ws + o_wt);
        unsigned short* fbf = (unsigned short*)(ws + o_fbf);

        const long n8 = (long)N * D / 8;
        const int nConvF = (int)((n8 + 255) / 256);
        const int nConvW = (D * D / 4 + 255) / 256;

        hipMemsetAsync(ctr, 0, 4, stream);

        prep_kernel<<<nConvF + nConvW + NB_P, 256, 0, stream>>>(
            feature, fbf, n8, W, Wt, dst, blockHist, E, K, chunk, nConvF, nConvW);

        claimB_kernel<<<(K + 255) / 256, 256, 0, stream>>>(
            blockHist, bbeg, bcnt, gcur, ctr, K);

        scatterB_kernel<<<NB_P, 256, 0, stream>>>(
            src, dst, blockHist, gcur, csrPacked, E, K, chunk);

        agg_gemm_kernel<<<(N + TN - 1) / TN, 256, 0, stream>>>(
            fbf, csrPacked, bbeg, bcnt, Wt, b, out, N);
    } else {
        hipMemsetAsync(d_out, 0, (size_t)out_size * sizeof(float), stream);
        scatter_kernel<<<(E + 3) / 4, 256, 0, stream>>>(feature, src, dst, out, E);
        linear_relu_kernel<<<(N + BM - 1) / BM, 256, 0, stream>>>(out, W, b, N);
    }
}